// Round 5
// baseline (1351.661 us; speedup 1.0000x reference)
//
#include <hip/hip_runtime.h>

// Problem: B=2, S=2304, C=1280, NH=8, DH=160, MH=64, SR=48, BH=16
// Established: ALL float inputs are fp32 (R1 NaN probe + detector); OUTPUT is fp32
// (reference returns jnp.float32; harness contract: non-bf16 ref -> float*).
// Internals in bf16 for MFMA; fp32 accumulation everywhere.

typedef unsigned short u16;
typedef unsigned int   u32;
typedef unsigned char  u8;
typedef __attribute__((ext_vector_type(8))) short bf16x8;   // 8 bf16 = 4 VGPRs
typedef __attribute__((ext_vector_type(4))) float f32x4;

#define MFMA16(a,b,c) __builtin_amdgcn_mfma_f32_16x16x32_bf16((a),(b),(c),0,0,0)

__device__ __forceinline__ u16 f2b(float f) {            // fp32 -> bf16 RNE
  u32 u = __float_as_uint(f);
  return (u16)((u + 0x7fffu + ((u >> 16) & 1u)) >> 16);
}
__device__ __forceinline__ float b2f(u16 v) { return __uint_as_float(((u32)v) << 16); }

// ---------------- mask-mode detector: 0=i32, 1=u8, 2=bf16, 3=f32 ----------------
__global__ __launch_bounds__(256) void maskdet(const u32* __restrict__ mid, u32* mode)
{
  __shared__ int a0, a1, a2, a3;
  int tid = threadIdx.x;
  if (tid == 0) { a0 = 1; a1 = 1; a2 = 1; a3 = 0; }
  __syncthreads();
  #pragma unroll
  for (int j = 0; j < 4; j++) {
    u32 w = mid[tid*4 + j];                      // first 4 KiB, in-bounds for all dtypes
    if (w > 1u)                      atomicAnd(&a0, 0);  // not i32 bools
    if (w & 0xFEFEFEFEu)             atomicAnd(&a1, 0);  // not u8 bools
    if (w != 0u && w != 0x3F800000u) atomicAnd(&a2, 0);  // not f32 {0,1}
    if ((w & 0xFFFFu) == 0x3F80u)    atomicOr(&a3, 1);   // bf16 1.0 in low half
  }
  __syncthreads();
  if (tid == 0) mode[0] = a0 ? 0u : (a1 ? 1u : (a3 ? 2u : (a2 ? 3u : 0u)));
}

// ---------------- nearest-downsample masks 64x64 -> 48x48 flattened to S ----------------
__global__ void maskprep(const void* mid, const float* __restrict__ mig_in,
                         float* __restrict__ mk, float* __restrict__ mg, const u32* mode)
{
  int j = blockIdx.x*256 + threadIdx.x;
  if (j >= 2*2304) return;
  u32 md = mode[0];
  int b = j / 2304, s = j % 2304;
  int i = s / 48, jj = s % 48;
  int ih = (i*4)/3, iw = (jj*4)/3;        // arange(48)*64//48
  int src = b*4096 + ih*64 + iw;
  bool on;
  if      (md == 0) on = ((const int*)mid)[src] != 0;
  else if (md == 1) on = ((const u8*)mid)[src]  != 0;
  else if (md == 2) on = ((const u16*)mid)[src] != 0;
  else              on = ((const float*)mid)[src] != 0.0f;
  mk[j] = on ? 1.0f : 0.0f;
  mg[j] = mig_in[src];                     // mask_ig is fp32
}

// ---------------- transpose weights: fp32 W[k][n] -> bf16 WT[n][k], 4 matrices --------------
__global__ __launch_bounds__(256) void transpose_w(
    const float* __restrict__ W0, const float* __restrict__ W1,
    const float* __restrict__ W2, const float* __restrict__ W3, u16* __restrict__ WT)
{
  __shared__ u16 t[32][33];
  int z = blockIdx.z;
  const float* s = (z==0)?W0:(z==1)?W1:(z==2)?W2:W3;
  u16* d = WT + (size_t)z*1280*1280;
  int tx = threadIdx.x & 31, ty = (threadIdx.x >> 5) * 4;
  int x = blockIdx.x*32 + tx;          // src col (n)
  int y = blockIdx.y*32 + ty;          // src row (k)
  #pragma unroll
  for (int i=0;i<4;i++) t[ty+i][tx] = f2b(s[(size_t)(y+i)*1280 + x]);
  __syncthreads();
  int x2 = blockIdx.y*32 + tx, y2 = blockIdx.x*32 + ty;
  #pragma unroll
  for (int i=0;i<4;i++) d[(size_t)(y2+i)*1280 + x2] = t[tx][ty+i];   // WT[n][k] = W[k][n]
}

// ---------------- convert fp32 -> bf16 ----------------
__global__ __launch_bounds__(256) void conv(const float* __restrict__ src, u16* __restrict__ dst, int n)
{
  for (int i = blockIdx.x*256 + threadIdx.x; i < n; i += gridDim.x*256)
    dst[i] = f2b(src[i]);
}

// ---------------- transpose store_vs fp32 [16][2304][160] -> bf16 vst[16][160][2304] ---------
__global__ __launch_bounds__(256) void transpose_vs(const float* __restrict__ src, u16* __restrict__ dst)
{
  __shared__ u16 t[32][33];
  int z = blockIdx.z;
  u16* d = dst + (size_t)z*160*2304;
  int tx = threadIdx.x & 31, ty = (threadIdx.x >> 5) * 4;
  int r0 = blockIdx.x*32, c0 = blockIdx.y*32;
  #pragma unroll
  for (int i=0;i<4;i++)
    t[ty+i][tx] = f2b(src[((size_t)z*2304 + r0+ty+i)*160 + c0+tx]);
  __syncthreads();
  #pragma unroll
  for (int i=0;i<4;i++) d[(size_t)(c0+ty+i)*2304 + r0+tx] = t[tx][ty+i]; // d[c][r] = s[r][c]
}

// ---------------- GEMM: 128x128 tile, BK=32, 4 waves (2x2), 16x16x32 MFMA ----------------
// kind 0: A=hidB, BT=WT[z]; z=0->q, z=1->k (both [bh][s][d]), z=2->v^T [bh][d][s]
// kind 1: A=comb, BT=WoT;   out = A@Wo + bias -> fp32 d_out
__global__ __launch_bounds__(256) void gemm128(
    const u16* __restrict__ A, const u16* __restrict__ BT,
    u16* __restrict__ dq, u16* __restrict__ dk, u16* __restrict__ dvt,
    float* __restrict__ dout, const float* __restrict__ bias, int kind)
{
  __shared__ __align__(16) u16 As[128*40];   // pad 32->40: 80B stride breaks conflicts
  __shared__ __align__(16) u16 Bs[128*40];
  int tid = threadIdx.x;
  int m0 = blockIdx.x*128, n0 = blockIdx.y*128;
  int z = blockIdx.z;
  const u16* Bt = BT + (size_t)z*1280*1280;
  int w = tid>>6, lane = tid&63, quad = lane>>4, l16 = lane&15;
  int wm = w&1, wn = w>>1;
  int arow = tid>>1, acg = (tid&1)*16;
  f32x4 zero = {0.f,0.f,0.f,0.f};
  f32x4 acc[4][4];
  #pragma unroll
  for (int a=0;a<4;a++) { acc[a][0]=zero; acc[a][1]=zero; acc[a][2]=zero; acc[a][3]=zero; }
  const u16* ga = A  + (size_t)(m0+arow)*1280 + acg;
  const u16* gb = Bt + (size_t)(n0+arow)*1280 + acg;
  for (int k0 = 0; k0 < 1280; k0 += 32) {
    uint4 a0 = *(const uint4*)(ga + k0);
    uint4 a1 = *(const uint4*)(ga + k0 + 8);
    uint4 b0 = *(const uint4*)(gb + k0);
    uint4 b1 = *(const uint4*)(gb + k0 + 8);
    __syncthreads();
    *(uint4*)&As[arow*40 + acg]     = a0;
    *(uint4*)&As[arow*40 + acg + 8] = a1;
    *(uint4*)&Bs[arow*40 + acg]     = b0;
    *(uint4*)&Bs[arow*40 + acg + 8] = b1;
    __syncthreads();
    bf16x8 af[4], bfr[4];
    #pragma unroll
    for (int mt=0; mt<4; mt++) af[mt]  = *(const bf16x8*)&As[(wm*64+mt*16+l16)*40 + quad*8];
    #pragma unroll
    for (int nt=0; nt<4; nt++) bfr[nt] = *(const bf16x8*)&Bs[(wn*64+nt*16+l16)*40 + quad*8];
    #pragma unroll
    for (int mt=0; mt<4; mt++)
      #pragma unroll
      for (int nt=0; nt<4; nt++)
        acc[mt][nt] = MFMA16(af[mt], bfr[nt], acc[mt][nt]);
  }
  #pragma unroll
  for (int mt=0; mt<4; mt++) {
    int r0g = m0 + wm*64 + mt*16 + quad*4;          // 4 consecutive rows (reg 0..3)
    #pragma unroll
    for (int nt=0; nt<4; nt++) {
      int col = n0 + wn*64 + nt*16 + l16;
      if (kind == 1) {
        float bi = bias[col];
        #pragma unroll
        for (int r=0;r<4;r++) dout[(size_t)(r0g+r)*1280 + col] = acc[mt][nt][r] + bi;
      } else {
        int h = col/160, d = col%160;
        if (z == 2) {                               // v -> [bh][d][s], s consecutive
          int b = r0g/2304, s0 = r0g%2304;
          size_t base = ((size_t)((b*8+h)*160 + d))*2304 + s0;
          ushort4 pk;
          pk.x = f2b(acc[mt][nt][0]); pk.y = f2b(acc[mt][nt][1]);
          pk.z = f2b(acc[mt][nt][2]); pk.w = f2b(acc[mt][nt][3]);
          *(ushort4*)&dvt[base] = pk;
        } else {                                    // q/k -> h2b layout [bh][s][d]
          u16* dst = (z==0)? dq : dk;
          #pragma unroll
          for (int r=0;r<4;r++) {
            int rg = r0g + r;
            int b = rg/2304, s = rg%2304;
            dst[((size_t)(b*8+h)*2304 + s)*160 + d] = f2b(acc[mt][nt][r]);
          }
        }
      }
    }
  }
}

// ---------------- Attention (flash-style, online softmax). ip=0: self -> hs (bf16).
// ip=1: keys=sksB, V=vst, per-key mask (bh%B tile quirk), combine -> comb bf16. --------
__global__ __launch_bounds__(256) void attn(
    const u16* __restrict__ qg,   // [16][2304][160]
    const u16* __restrict__ kg,   // [16][2304][160]
    const u16* __restrict__ vtg,  // [16][160][2304]
    const float* __restrict__ maskkey, const float* __restrict__ mig,
    u16* __restrict__ hs, u16* __restrict__ comb,
    const void* scaleptr, int ip)
{
  __shared__ __align__(16) u16 Ks[64*168];    // keys x d, pad 160->168
  __shared__ __align__(16) u16 VTs[160*72];   // d x keys, pad 64->72
  __shared__ __align__(16) u16 Ps[4*16*72];   // per-wave P relayout buffer
  int bh = blockIdx.y, qt = blockIdx.x;
  int tid = threadIdx.x, w = tid>>6, lane = tid&63, quad = lane>>4, l16 = lane&15;
  int q0 = qt*64 + w*16;                       // wave's 16 queries
  const float inv = 0.07905694150420949f;      // 1/sqrt(160)

  bf16x8 aq[5];                                // Q frags: A[m=l16][k=quad*8+j], 5 ksteps
  {
    const u16* qrow = qg + ((size_t)bh*2304 + q0 + l16)*160 + quad*8;
    #pragma unroll
    for (int ks=0; ks<5; ks++) aq[ks] = *(const bf16x8*)(qrow + ks*32);
  }
  f32x4 zero = {0.f,0.f,0.f,0.f};
  f32x4 o[10];
  #pragma unroll
  for (int i=0;i<10;i++) o[i] = zero;
  float mrun[4] = {-1e30f,-1e30f,-1e30f,-1e30f};
  float lrun[4] = {0.f,0.f,0.f,0.f};

  int krow = tid>>2, kcg = (tid&3)*40;
  const u16* kbase = kg + ((size_t)bh*2304 + krow)*160 + kcg;

  for (int kc = 0; kc < 36; kc++) {
    uint4 kv[5], vv[5];
    #pragma unroll
    for (int i=0;i<5;i++) kv[i] = *(const uint4*)(kbase + (size_t)kc*64*160 + i*8);
    #pragma unroll
    for (int i=0;i<5;i++) {
      int idx = i*256 + tid;
      int d = idx>>3, cg = (idx&7)*8;
      vv[i] = *(const uint4*)(vtg + ((size_t)bh*160 + d)*2304 + kc*64 + cg);
    }
    __syncthreads();                       // prior iter's LDS reads done
    #pragma unroll
    for (int i=0;i<5;i++) *(uint4*)&Ks[krow*168 + kcg + i*8] = kv[i];
    #pragma unroll
    for (int i=0;i<5;i++) {
      int idx = i*256 + tid;
      int d = idx>>3, cg = (idx&7)*8;
      *(uint4*)&VTs[d*72 + cg] = vv[i];
    }
    __syncthreads();

    // scores S[16 q][64 keys] = Q K^T * inv (+ mask)
    f32x4 sc[4];
    bool keep[4];
    #pragma unroll
    for (int nt=0; nt<4; nt++) {
      f32x4 s = zero;
      #pragma unroll
      for (int ks=0; ks<5; ks++) {
        bf16x8 bk = *(const bf16x8*)&Ks[(nt*16+l16)*168 + ks*32 + quad*8];
        s = MFMA16(aq[ks], bk, s);
      }
      #pragma unroll
      for (int r=0;r<4;r++) s[r] *= inv;
      keep[nt] = true;
      if (ip) {
        int key = kc*64 + nt*16 + l16;
        // diffusers .repeat(NH,1,1): mask batch index = bh % B, NOT bh/NH
        if (maskkey[(bh & 1)*2304 + key] == 0.0f) {
          keep[nt] = false;
          #pragma unroll
          for (int r=0;r<4;r++) s[r] = -1e30f;
        }
      }
      sc[nt] = s;
    }

    // online softmax per query row (row = quad*4+r, 16 key-cols across the quad's lanes)
    float p[4][4];
    #pragma unroll
    for (int r=0;r<4;r++) {
      float mrow = fmaxf(fmaxf(sc[0][r], sc[1][r]), fmaxf(sc[2][r], sc[3][r]));
      #pragma unroll
      for (int off=1; off<16; off<<=1) mrow = fmaxf(mrow, __shfl_xor(mrow, off));
      float nm = fmaxf(mrun[r], mrow);
      float alpha = __expf(fminf(mrun[r] - nm, 0.f));
      mrun[r] = nm;
      float rs = 0.f;
      #pragma unroll
      for (int nt=0;nt<4;nt++) {
        float e = keep[nt] ? __expf(sc[nt][r] - nm) : 0.f;
        p[nt][r] = e; rs += e;
      }
      #pragma unroll
      for (int off=1; off<16; off<<=1) rs += __shfl_xor(rs, off);
      lrun[r] = lrun[r]*alpha + rs;
      #pragma unroll
      for (int nt2=0; nt2<10; nt2++) o[nt2][r] *= alpha;
    }

    // P: C-layout -> A-layout via LDS (barrier-insured round-trip this round)
    __syncthreads();
    #pragma unroll
    for (int nt=0;nt<4;nt++)
      #pragma unroll
      for (int r=0;r<4;r++)
        Ps[(w*16 + quad*4 + r)*72 + nt*16 + l16] = f2b(p[nt][r]);
    __syncthreads();

    // O += P V
    #pragma unroll
    for (int kb=0; kb<2; kb++) {
      bf16x8 ap = *(const bf16x8*)&Ps[(w*16 + l16)*72 + kb*32 + quad*8];
      #pragma unroll
      for (int nt=0; nt<10; nt++) {
        bf16x8 bv = *(const bf16x8*)&VTs[(nt*16+l16)*72 + kb*32 + quad*8];
        o[nt] = MFMA16(ap, bv, o[nt]);
      }
    }
  }

  // epilogue
  int b = bh>>3, h = bh&7;
  float scl = 0.f;
  if (ip) {                                   // scalar dtype self-detect (0.5 decodes both ways)
    u16 v0 = ((const u16*)scaleptr)[0];
    int e = (v0 >> 7) & 0xFF;
    scl = (v0 != 0 && e >= 100 && e <= 133) ? b2f(v0) : ((const float*)scaleptr)[0];
  }
  #pragma unroll
  for (int r=0;r<4;r++) {
    int s = q0 + quad*4 + r;
    float linv = (lrun[r] > 0.f) ? 1.0f/lrun[r] : 0.f;
    size_t base = ((size_t)b*2304 + s)*1280 + h*160;
    if (!ip) {
      #pragma unroll
      for (int nt=0;nt<10;nt++) hs[base + nt*16 + l16] = f2b(o[nt][r]*linv);
    } else {
      float f = mig[b*2304 + s]*scl*linv;    // mig uses TRUE b
      #pragma unroll
      for (int nt=0;nt<10;nt++)
        comb[base + nt*16 + l16] = f2b(b2f(hs[base + nt*16 + l16]) + o[nt][r]*f);
    }
  }
}

// ---------------- launch ----------------
extern "C" void kernel_launch(void* const* d_in, const int* in_sizes, int n_in,
                              void* d_out, int out_size, void* d_ws, size_t ws_size,
                              hipStream_t stream)
{
  const float* hid = (const float*)d_in[0];
  const float* Wq  = (const float*)d_in[1];
  const float* Wk  = (const float*)d_in[2];
  const float* Wv  = (const float*)d_in[3];
  const float* Wo  = (const float*)d_in[4];
  const float* bo  = (const float*)d_in[5];
  const float* sks = (const float*)d_in[6];
  const float* svs = (const float*)d_in[7];
  const void*  mid = d_in[8];
  const float* mig = (const float*)d_in[9];
  const void*  scl = d_in[10];

  char* ws = (char*)d_ws;                    // 72.13 MiB total (aliased, stream-ordered)
  float* mk   = (float*)(ws);                // [2][2304]              18432 B
  float* mg   = (float*)(ws + 18432);        // [2][2304]              18432 B
  u32*  mode  = (u32*)(ws + 36864);          // 256 B
  u16*  WT    = (u16*)(ws + 40960);          // 4 x 1280x1280 bf16  13107200 B
  u16*  hidB  = (u16*)(ws + 13148160);       // hid bf16; REUSED as sksB    11796480
  u16*  q     = (u16*)(ws + 24944640);       // [16][2304][160]             11796480
  u16*  kB    = (u16*)(ws + 36741120);       // k bf16; REUSED as comb      11796480
  u16*  vt    = (u16*)(ws + 48537600);       // v^T; REUSED as vst          11796480
  u16*  hsB   = (u16*)(ws + 60334080);       // self-attn out bf16          11796480

  maskdet     <<<dim3(1),       256, 0, stream>>>((const u32*)mid, mode);
  maskprep    <<<dim3(18),      256, 0, stream>>>(mid, mig, mk, mg, mode);
  transpose_w <<<dim3(40,40,4), 256, 0, stream>>>(Wq, Wk, Wv, Wo, WT);
  conv        <<<dim3(2880),    256, 0, stream>>>(hid, hidB, 5898240);
  gemm128     <<<dim3(36,10,3), 256, 0, stream>>>(hidB, WT, q, kB, vt, nullptr, nullptr, 0);
  conv        <<<dim3(2880),    256, 0, stream>>>(sks, hidB, 5898240);           // hidB dead -> sksB
  attn        <<<dim3(36,16),   256, 0, stream>>>(q, kB, vt, nullptr, nullptr, hsB, nullptr, scl, 0);
  transpose_vs<<<dim3(72,5,16), 256, 0, stream>>>(svs, vt);                      // vt dead -> vst
  attn        <<<dim3(36,16),   256, 0, stream>>>(q, hidB, vt, mk, mg, hsB, kB, scl, 1); // kB dead -> comb
  gemm128     <<<dim3(36,10,1), 256, 0, stream>>>(kB, WT + (size_t)3*1280*1280,
                                                  nullptr, nullptr, nullptr, (float*)d_out, bo, 1);
}

// Round 6
// 1071.023 us; speedup vs baseline: 1.2620x; 1.2620x over previous
//
#include <hip/hip_runtime.h>

// Problem: B=2, S=2304, C=1280, NH=8, DH=160, MH=64, SR=48, BH=16
// Established: float inputs fp32, output fp32, mask via mini-detector.
// R5 passed at 1352us; attn dominated (2x562us) by scratch-spill write traffic
// (737MB/dispatch, VGPR capped at 88). R6: launch_bounds(256,2) + drop VTs stage.

typedef unsigned short u16;
typedef unsigned int   u32;
typedef unsigned char  u8;
typedef __attribute__((ext_vector_type(8))) short bf16x8;   // 8 bf16 = 4 VGPRs
typedef __attribute__((ext_vector_type(4))) float f32x4;

#define MFMA16(a,b,c) __builtin_amdgcn_mfma_f32_16x16x32_bf16((a),(b),(c),0,0,0)

__device__ __forceinline__ u16 f2b(float f) {            // fp32 -> bf16 RNE
  u32 u = __float_as_uint(f);
  return (u16)((u + 0x7fffu + ((u >> 16) & 1u)) >> 16);
}
__device__ __forceinline__ float b2f(u16 v) { return __uint_as_float(((u32)v) << 16); }

// ---------------- mask-mode detector: 0=i32, 1=u8, 2=bf16, 3=f32 ----------------
__global__ __launch_bounds__(256) void maskdet(const u32* __restrict__ mid, u32* mode)
{
  __shared__ int a0, a1, a2, a3;
  int tid = threadIdx.x;
  if (tid == 0) { a0 = 1; a1 = 1; a2 = 1; a3 = 0; }
  __syncthreads();
  #pragma unroll
  for (int j = 0; j < 4; j++) {
    u32 w = mid[tid*4 + j];                      // first 4 KiB, in-bounds for all dtypes
    if (w > 1u)                      atomicAnd(&a0, 0);  // not i32 bools
    if (w & 0xFEFEFEFEu)             atomicAnd(&a1, 0);  // not u8 bools
    if (w != 0u && w != 0x3F800000u) atomicAnd(&a2, 0);  // not f32 {0,1}
    if ((w & 0xFFFFu) == 0x3F80u)    atomicOr(&a3, 1);   // bf16 1.0 in low half
  }
  __syncthreads();
  if (tid == 0) mode[0] = a0 ? 0u : (a1 ? 1u : (a3 ? 2u : (a2 ? 3u : 0u)));
}

// ---------------- nearest-downsample masks 64x64 -> 48x48 flattened to S ----------------
__global__ void maskprep(const void* mid, const float* __restrict__ mig_in,
                         float* __restrict__ mk, float* __restrict__ mg, const u32* mode)
{
  int j = blockIdx.x*256 + threadIdx.x;
  if (j >= 2*2304) return;
  u32 md = mode[0];
  int b = j / 2304, s = j % 2304;
  int i = s / 48, jj = s % 48;
  int ih = (i*4)/3, iw = (jj*4)/3;        // arange(48)*64//48
  int src = b*4096 + ih*64 + iw;
  bool on;
  if      (md == 0) on = ((const int*)mid)[src] != 0;
  else if (md == 1) on = ((const u8*)mid)[src]  != 0;
  else if (md == 2) on = ((const u16*)mid)[src] != 0;
  else              on = ((const float*)mid)[src] != 0.0f;
  mk[j] = on ? 1.0f : 0.0f;
  mg[j] = mig_in[src];                     // mask_ig is fp32
}

// ---------------- transpose weights: fp32 W[k][n] -> bf16 WT[n][k], 4 matrices --------------
__global__ __launch_bounds__(256) void transpose_w(
    const float* __restrict__ W0, const float* __restrict__ W1,
    const float* __restrict__ W2, const float* __restrict__ W3, u16* __restrict__ WT)
{
  __shared__ u16 t[32][33];
  int z = blockIdx.z;
  const float* s = (z==0)?W0:(z==1)?W1:(z==2)?W2:W3;
  u16* d = WT + (size_t)z*1280*1280;
  int tx = threadIdx.x & 31, ty = (threadIdx.x >> 5) * 4;
  int x = blockIdx.x*32 + tx;          // src col (n)
  int y = blockIdx.y*32 + ty;          // src row (k)
  #pragma unroll
  for (int i=0;i<4;i++) t[ty+i][tx] = f2b(s[(size_t)(y+i)*1280 + x]);
  __syncthreads();
  int x2 = blockIdx.y*32 + tx, y2 = blockIdx.x*32 + ty;
  #pragma unroll
  for (int i=0;i<4;i++) d[(size_t)(y2+i)*1280 + x2] = t[tx][ty+i];   // WT[n][k] = W[k][n]
}

// ---------------- convert fp32 -> bf16 ----------------
__global__ __launch_bounds__(256) void conv(const float* __restrict__ src, u16* __restrict__ dst, int n)
{
  for (int i = blockIdx.x*256 + threadIdx.x; i < n; i += gridDim.x*256)
    dst[i] = f2b(src[i]);
}

// ---------------- transpose store_vs fp32 [16][2304][160] -> bf16 vst[16][160][2304] ---------
__global__ __launch_bounds__(256) void transpose_vs(const float* __restrict__ src, u16* __restrict__ dst)
{
  __shared__ u16 t[32][33];
  int z = blockIdx.z;
  u16* d = dst + (size_t)z*160*2304;
  int tx = threadIdx.x & 31, ty = (threadIdx.x >> 5) * 4;
  int r0 = blockIdx.x*32, c0 = blockIdx.y*32;
  #pragma unroll
  for (int i=0;i<4;i++)
    t[ty+i][tx] = f2b(src[((size_t)z*2304 + r0+ty+i)*160 + c0+tx]);
  __syncthreads();
  #pragma unroll
  for (int i=0;i<4;i++) d[(size_t)(c0+ty+i)*2304 + r0+tx] = t[tx][ty+i]; // d[c][r] = s[r][c]
}

// ---------------- GEMM: 128x128 tile, BK=32, 4 waves (2x2), 16x16x32 MFMA ----------------
// kind 0: A=hidB, BT=WT[z]; z=0->q, z=1->k (both [bh][s][d]), z=2->v^T [bh][d][s]
// kind 1: A=comb, BT=WoT;   out = A@Wo + bias -> fp32 d_out
__global__ __launch_bounds__(256, 2) void gemm128(
    const u16* __restrict__ A, const u16* __restrict__ BT,
    u16* __restrict__ dq, u16* __restrict__ dk, u16* __restrict__ dvt,
    float* __restrict__ dout, const float* __restrict__ bias, int kind)
{
  __shared__ __align__(16) u16 As[128*40];   // pad 32->40: 80B stride breaks conflicts
  __shared__ __align__(16) u16 Bs[128*40];
  int tid = threadIdx.x;
  int m0 = blockIdx.x*128, n0 = blockIdx.y*128;
  int z = blockIdx.z;
  const u16* Bt = BT + (size_t)z*1280*1280;
  int w = tid>>6, lane = tid&63, quad = lane>>4, l16 = lane&15;
  int wm = w&1, wn = w>>1;
  int arow = tid>>1, acg = (tid&1)*16;
  f32x4 zero = {0.f,0.f,0.f,0.f};
  f32x4 acc[4][4];
  #pragma unroll
  for (int a=0;a<4;a++) { acc[a][0]=zero; acc[a][1]=zero; acc[a][2]=zero; acc[a][3]=zero; }
  const u16* ga = A  + (size_t)(m0+arow)*1280 + acg;
  const u16* gb = Bt + (size_t)(n0+arow)*1280 + acg;
  for (int k0 = 0; k0 < 1280; k0 += 32) {
    uint4 a0 = *(const uint4*)(ga + k0);
    uint4 a1 = *(const uint4*)(ga + k0 + 8);
    uint4 b0 = *(const uint4*)(gb + k0);
    uint4 b1 = *(const uint4*)(gb + k0 + 8);
    __syncthreads();
    *(uint4*)&As[arow*40 + acg]     = a0;
    *(uint4*)&As[arow*40 + acg + 8] = a1;
    *(uint4*)&Bs[arow*40 + acg]     = b0;
    *(uint4*)&Bs[arow*40 + acg + 8] = b1;
    __syncthreads();
    bf16x8 af[4], bfr[4];
    #pragma unroll
    for (int mt=0; mt<4; mt++) af[mt]  = *(const bf16x8*)&As[(wm*64+mt*16+l16)*40 + quad*8];
    #pragma unroll
    for (int nt=0; nt<4; nt++) bfr[nt] = *(const bf16x8*)&Bs[(wn*64+nt*16+l16)*40 + quad*8];
    #pragma unroll
    for (int mt=0; mt<4; mt++)
      #pragma unroll
      for (int nt=0; nt<4; nt++)
        acc[mt][nt] = MFMA16(af[mt], bfr[nt], acc[mt][nt]);
  }
  #pragma unroll
  for (int mt=0; mt<4; mt++) {
    int r0g = m0 + wm*64 + mt*16 + quad*4;          // 4 consecutive rows (reg 0..3)
    #pragma unroll
    for (int nt=0; nt<4; nt++) {
      int col = n0 + wn*64 + nt*16 + l16;
      if (kind == 1) {
        float bi = bias[col];
        #pragma unroll
        for (int r=0;r<4;r++) dout[(size_t)(r0g+r)*1280 + col] = acc[mt][nt][r] + bi;
      } else {
        int h = col/160, d = col%160;
        if (z == 2) {                               // v -> [bh][d][s], s consecutive
          int b = r0g/2304, s0 = r0g%2304;
          size_t base = ((size_t)((b*8+h)*160 + d))*2304 + s0;
          ushort4 pk;
          pk.x = f2b(acc[mt][nt][0]); pk.y = f2b(acc[mt][nt][1]);
          pk.z = f2b(acc[mt][nt][2]); pk.w = f2b(acc[mt][nt][3]);
          *(ushort4*)&dvt[base] = pk;
        } else {                                    // q/k -> h2b layout [bh][s][d]
          u16* dst = (z==0)? dq : dk;
          #pragma unroll
          for (int r=0;r<4;r++) {
            int rg = r0g + r;
            int b = rg/2304, s = rg%2304;
            dst[((size_t)(b*8+h)*2304 + s)*160 + d] = f2b(acc[mt][nt][r]);
          }
        }
      }
    }
  }
}

// ---------------- Attention (flash-style, online softmax). ip=0: self -> hs (bf16).
// ip=1: keys=sksB, V=vst, per-key mask (bh%B tile quirk), combine -> comb bf16.
// V B-frags read DIRECTLY from global (L1/L2 reuse); only K + P staged in LDS. --------
__global__ __launch_bounds__(256, 2) void attn(
    const u16* __restrict__ qg,   // [16][2304][160]
    const u16* __restrict__ kg,   // [16][2304][160]
    const u16* __restrict__ vtg,  // [16][160][2304]
    const float* __restrict__ maskkey, const float* __restrict__ mig,
    u16* __restrict__ hs, u16* __restrict__ comb,
    const void* scaleptr, int ip)
{
  __shared__ __align__(16) u16 Ks[64*168];    // keys x d, pad 160->168
  __shared__ __align__(16) u16 Ps[4*16*72];   // per-wave P relayout buffer
  int bh = blockIdx.y, qt = blockIdx.x;
  int tid = threadIdx.x, w = tid>>6, lane = tid&63, quad = lane>>4, l16 = lane&15;
  int q0 = qt*64 + w*16;                       // wave's 16 queries
  const float inv = 0.07905694150420949f;      // 1/sqrt(160)

  bf16x8 aq[5];                                // Q frags: A[m=l16][k=quad*8+j], 5 ksteps
  {
    const u16* qrow = qg + ((size_t)bh*2304 + q0 + l16)*160 + quad*8;
    #pragma unroll
    for (int ks=0; ks<5; ks++) aq[ks] = *(const bf16x8*)(qrow + ks*32);
  }
  f32x4 zero = {0.f,0.f,0.f,0.f};
  f32x4 o[10];
  #pragma unroll
  for (int i=0;i<10;i++) o[i] = zero;
  float mrun[4] = {-1e30f,-1e30f,-1e30f,-1e30f};
  float lrun[4] = {0.f,0.f,0.f,0.f};

  int krow = tid>>2, kcg = (tid&3)*40;
  const u16* kbase = kg + ((size_t)bh*2304 + krow)*160 + kcg;
  const u16* vbase = vtg + ((size_t)bh*160 + l16)*2304 + quad*8;   // + nt*16 rows + key offs

  for (int kc = 0; kc < 36; kc++) {
    // ---- stage K[64 keys][160 d] into LDS (VGPR transit, 20 regs) ----
    uint4 kv[5];
    #pragma unroll
    for (int i=0;i<5;i++) kv[i] = *(const uint4*)(kbase + (size_t)kc*64*160 + i*8);
    __syncthreads();                       // prior iter's Ks reads done
    #pragma unroll
    for (int i=0;i<5;i++) *(uint4*)&Ks[krow*168 + kcg + i*8] = kv[i];
    __syncthreads();

    // ---- scores S[16 q][64 keys] = Q K^T * inv (+ mask) ----
    f32x4 sc[4];
    bool keep[4];
    #pragma unroll
    for (int nt=0; nt<4; nt++) {
      f32x4 s = zero;
      #pragma unroll
      for (int ks=0; ks<5; ks++) {
        bf16x8 bk = *(const bf16x8*)&Ks[(nt*16+l16)*168 + ks*32 + quad*8];
        s = MFMA16(aq[ks], bk, s);
      }
      #pragma unroll
      for (int r=0;r<4;r++) s[r] *= inv;
      keep[nt] = true;
      if (ip) {
        int key = kc*64 + nt*16 + l16;
        // diffusers .repeat(NH,1,1): mask batch index = bh % B, NOT bh/NH
        if (maskkey[(bh & 1)*2304 + key] == 0.0f) {
          keep[nt] = false;
          #pragma unroll
          for (int r=0;r<4;r++) s[r] = -1e30f;
        }
      }
      sc[nt] = s;
    }

    // ---- online softmax per query row (row = quad*4+r) ----
    float p[4][4];
    #pragma unroll
    for (int r=0;r<4;r++) {
      float mrow = fmaxf(fmaxf(sc[0][r], sc[1][r]), fmaxf(sc[2][r], sc[3][r]));
      #pragma unroll
      for (int off=1; off<16; off<<=1) mrow = fmaxf(mrow, __shfl_xor(mrow, off));
      float nm = fmaxf(mrun[r], mrow);
      float alpha = __expf(fminf(mrun[r] - nm, 0.f));
      mrun[r] = nm;
      float rs = 0.f;
      #pragma unroll
      for (int nt=0;nt<4;nt++) {
        float e = keep[nt] ? __expf(sc[nt][r] - nm) : 0.f;
        p[nt][r] = e; rs += e;
      }
      #pragma unroll
      for (int off=1; off<16; off<<=1) rs += __shfl_xor(rs, off);
      lrun[r] = lrun[r]*alpha + rs;
      #pragma unroll
      for (int nt2=0; nt2<10; nt2++) o[nt2][r] *= alpha;
    }

    // ---- P: C-layout -> A-layout via per-wave LDS (same-wave DS ops are ordered;
    //      no cross-wave sharing -> no barrier) ----
    #pragma unroll
    for (int nt=0;nt<4;nt++)
      #pragma unroll
      for (int r=0;r<4;r++)
        Ps[(w*16 + quad*4 + r)*72 + nt*16 + l16] = f2b(p[nt][r]);

    // ---- O += P V, V B-frags straight from global (16B/lane, L1-resident tile) ----
    #pragma unroll
    for (int kb=0; kb<2; kb++) {
      bf16x8 ap = *(const bf16x8*)&Ps[(w*16 + l16)*72 + kb*32 + quad*8];
      #pragma unroll
      for (int nt=0; nt<10; nt++) {
        bf16x8 bv = *(const bf16x8*)(vbase + (size_t)nt*16*2304 + kc*64 + kb*32);
        o[nt] = MFMA16(ap, bv, o[nt]);
      }
    }
  }

  // ---- epilogue ----
  int b = bh>>3, h = bh&7;
  float scl = 0.f;
  if (ip) {                                   // scalar dtype self-detect (0.5 decodes both ways)
    u16 v0 = ((const u16*)scaleptr)[0];
    int e = (v0 >> 7) & 0xFF;
    scl = (v0 != 0 && e >= 100 && e <= 133) ? b2f(v0) : ((const float*)scaleptr)[0];
  }
  #pragma unroll
  for (int r=0;r<4;r++) {
    int s = q0 + quad*4 + r;
    float linv = (lrun[r] > 0.f) ? 1.0f/lrun[r] : 0.f;
    size_t base = ((size_t)b*2304 + s)*1280 + h*160;
    if (!ip) {
      #pragma unroll
      for (int nt=0;nt<10;nt++) hs[base + nt*16 + l16] = f2b(o[nt][r]*linv);
    } else {
      float f = mig[b*2304 + s]*scl*linv;    // mig uses TRUE b
      #pragma unroll
      for (int nt=0;nt<10;nt++)
        comb[base + nt*16 + l16] = f2b(b2f(hs[base + nt*16 + l16]) + o[nt][r]*f);
    }
  }
}

// ---------------- launch ----------------
extern "C" void kernel_launch(void* const* d_in, const int* in_sizes, int n_in,
                              void* d_out, int out_size, void* d_ws, size_t ws_size,
                              hipStream_t stream)
{
  const float* hid = (const float*)d_in[0];
  const float* Wq  = (const float*)d_in[1];
  const float* Wk  = (const float*)d_in[2];
  const float* Wv  = (const float*)d_in[3];
  const float* Wo  = (const float*)d_in[4];
  const float* bo  = (const float*)d_in[5];
  const float* sks = (const float*)d_in[6];
  const float* svs = (const float*)d_in[7];
  const void*  mid = d_in[8];
  const float* mig = (const float*)d_in[9];
  const void*  scl = d_in[10];

  char* ws = (char*)d_ws;                    // 72.13 MiB total (aliased, stream-ordered)
  float* mk   = (float*)(ws);                // [2][2304]              18432 B
  float* mg   = (float*)(ws + 18432);        // [2][2304]              18432 B
  u32*  mode  = (u32*)(ws + 36864);          // 256 B
  u16*  WT    = (u16*)(ws + 40960);          // 4 x 1280x1280 bf16  13107200 B
  u16*  hidB  = (u16*)(ws + 13148160);       // hid bf16; REUSED as sksB    11796480
  u16*  q     = (u16*)(ws + 24944640);       // [16][2304][160]             11796480
  u16*  kB    = (u16*)(ws + 36741120);       // k bf16; REUSED as comb      11796480
  u16*  vt    = (u16*)(ws + 48537600);       // v^T; REUSED as vst          11796480
  u16*  hsB   = (u16*)(ws + 60334080);       // self-attn out bf16          11796480

  maskdet     <<<dim3(1),       256, 0, stream>>>((const u32*)mid, mode);
  maskprep    <<<dim3(18),      256, 0, stream>>>(mid, mig, mk, mg, mode);
  transpose_w <<<dim3(40,40,4), 256, 0, stream>>>(Wq, Wk, Wv, Wo, WT);
  conv        <<<dim3(2880),    256, 0, stream>>>(hid, hidB, 5898240);
  gemm128     <<<dim3(36,10,3), 256, 0, stream>>>(hidB, WT, q, kB, vt, nullptr, nullptr, 0);
  conv        <<<dim3(2880),    256, 0, stream>>>(sks, hidB, 5898240);           // hidB dead -> sksB
  attn        <<<dim3(36,16),   256, 0, stream>>>(q, kB, vt, nullptr, nullptr, hsB, nullptr, scl, 0);
  transpose_vs<<<dim3(72,5,16), 256, 0, stream>>>(svs, vt);                      // vt dead -> vst
  attn        <<<dim3(36,16),   256, 0, stream>>>(q, hidB, vt, mk, mg, hsB, kB, scl, 1); // kB dead -> comb
  gemm128     <<<dim3(36,10,1), 256, 0, stream>>>(kB, WT + (size_t)3*1280*1280,
                                                  nullptr, nullptr, nullptr, (float*)d_out, bo, 1);
}

// Round 7
// 958.097 us; speedup vs baseline: 1.4108x; 1.1179x over previous
//
#include <hip/hip_runtime.h>

// Problem: B=2, S=2304, C=1280, NH=8, DH=160, MH=64, SR=48, BH=16
// Established: float inputs fp32, output fp32, mask via mini-detector.
// R6: 1071us. attn spill traffic traced to kv[5] staging live across barrier
// (WRITE_SIZE 253MB vs 12MB intended). R7: K staged via global_load_lds DMA
// (padded [bh][s][168] K layout -> contiguous 21504B tiles, lane-linear).

typedef unsigned short u16;
typedef unsigned int   u32;
typedef unsigned char  u8;
typedef __attribute__((ext_vector_type(8))) short bf16x8;   // 8 bf16 = 4 VGPRs
typedef __attribute__((ext_vector_type(4))) float f32x4;

#define MFMA16(a,b,c) __builtin_amdgcn_mfma_f32_16x16x32_bf16((a),(b),(c),0,0,0)
#define KPAD 168                                      // K row stride (u16): 84 dw % 32 = 20 -> 2-way free

typedef const __attribute__((address_space(1))) void gvoid;
typedef __attribute__((address_space(3))) void lvoid;
#define GLD16(gp, lp) __builtin_amdgcn_global_load_lds((gvoid*)(gp), (lvoid*)(lp), 16, 0, 0)

__device__ __forceinline__ u16 f2b(float f) {            // fp32 -> bf16 RNE
  u32 u = __float_as_uint(f);
  return (u16)((u + 0x7fffu + ((u >> 16) & 1u)) >> 16);
}
__device__ __forceinline__ float b2f(u16 v) { return __uint_as_float(((u32)v) << 16); }

// ---------------- mask-mode detector: 0=i32, 1=u8, 2=bf16, 3=f32 ----------------
__global__ __launch_bounds__(256) void maskdet(const u32* __restrict__ mid, u32* mode)
{
  __shared__ int a0, a1, a2, a3;
  int tid = threadIdx.x;
  if (tid == 0) { a0 = 1; a1 = 1; a2 = 1; a3 = 0; }
  __syncthreads();
  #pragma unroll
  for (int j = 0; j < 4; j++) {
    u32 w = mid[tid*4 + j];                      // first 4 KiB, in-bounds for all dtypes
    if (w > 1u)                      atomicAnd(&a0, 0);  // not i32 bools
    if (w & 0xFEFEFEFEu)             atomicAnd(&a1, 0);  // not u8 bools
    if (w != 0u && w != 0x3F800000u) atomicAnd(&a2, 0);  // not f32 {0,1}
    if ((w & 0xFFFFu) == 0x3F80u)    atomicOr(&a3, 1);   // bf16 1.0 in low half
  }
  __syncthreads();
  if (tid == 0) mode[0] = a0 ? 0u : (a1 ? 1u : (a3 ? 2u : (a2 ? 3u : 0u)));
}

// ---------------- nearest-downsample masks 64x64 -> 48x48 flattened to S ----------------
__global__ void maskprep(const void* mid, const float* __restrict__ mig_in,
                         float* __restrict__ mk, float* __restrict__ mg, const u32* mode)
{
  int j = blockIdx.x*256 + threadIdx.x;
  if (j >= 2*2304) return;
  u32 md = mode[0];
  int b = j / 2304, s = j % 2304;
  int i = s / 48, jj = s % 48;
  int ih = (i*4)/3, iw = (jj*4)/3;        // arange(48)*64//48
  int src = b*4096 + ih*64 + iw;
  bool on;
  if      (md == 0) on = ((const int*)mid)[src] != 0;
  else if (md == 1) on = ((const u8*)mid)[src]  != 0;
  else if (md == 2) on = ((const u16*)mid)[src] != 0;
  else              on = ((const float*)mid)[src] != 0.0f;
  mk[j] = on ? 1.0f : 0.0f;
  mg[j] = mig_in[src];                     // mask_ig is fp32
}

// ---------------- transpose weights: fp32 W[k][n] -> bf16 WT[n][k], 4 matrices --------------
__global__ __launch_bounds__(256) void transpose_w(
    const float* __restrict__ W0, const float* __restrict__ W1,
    const float* __restrict__ W2, const float* __restrict__ W3, u16* __restrict__ WT)
{
  __shared__ u16 t[32][33];
  int z = blockIdx.z;
  const float* s = (z==0)?W0:(z==1)?W1:(z==2)?W2:W3;
  u16* d = WT + (size_t)z*1280*1280;
  int tx = threadIdx.x & 31, ty = (threadIdx.x >> 5) * 4;
  int x = blockIdx.x*32 + tx;          // src col (n)
  int y = blockIdx.y*32 + ty;          // src row (k)
  #pragma unroll
  for (int i=0;i<4;i++) t[ty+i][tx] = f2b(s[(size_t)(y+i)*1280 + x]);
  __syncthreads();
  int x2 = blockIdx.y*32 + tx, y2 = blockIdx.x*32 + ty;
  #pragma unroll
  for (int i=0;i<4;i++) d[(size_t)(y2+i)*1280 + x2] = t[tx][ty+i];   // WT[n][k] = W[k][n]
}

// ---------------- convert fp32 -> bf16 (unpadded) ----------------
__global__ __launch_bounds__(256) void conv(const float* __restrict__ src, u16* __restrict__ dst, int n)
{
  for (int i = blockIdx.x*256 + threadIdx.x; i < n; i += gridDim.x*256)
    dst[i] = f2b(src[i]);
}

// ---------------- convert store_ks fp32 [bh][s][160] -> padded bf16 [bh][s][168] ------------
__global__ __launch_bounds__(256) void convK(const float* __restrict__ src, u16* __restrict__ dst)
{
  const int n = 16*2304*KPAD;
  for (int i = blockIdx.x*256 + threadIdx.x; i < n; i += gridDim.x*256) {
    int row = i / KPAD, col = i % KPAD;
    dst[i] = (col < 160) ? f2b(src[(size_t)row*160 + col]) : (u16)0;
  }
}

// ---------------- transpose store_vs fp32 [16][2304][160] -> bf16 vst[16][160][2304] ---------
__global__ __launch_bounds__(256) void transpose_vs(const float* __restrict__ src, u16* __restrict__ dst)
{
  __shared__ u16 t[32][33];
  int z = blockIdx.z;
  u16* d = dst + (size_t)z*160*2304;
  int tx = threadIdx.x & 31, ty = (threadIdx.x >> 5) * 4;
  int r0 = blockIdx.x*32, c0 = blockIdx.y*32;
  #pragma unroll
  for (int i=0;i<4;i++)
    t[ty+i][tx] = f2b(src[((size_t)z*2304 + r0+ty+i)*160 + c0+tx]);
  __syncthreads();
  #pragma unroll
  for (int i=0;i<4;i++) d[(size_t)(c0+ty+i)*2304 + r0+tx] = t[tx][ty+i]; // d[c][r] = s[r][c]
}

// ---------------- GEMM: 128x128 tile, BK=32, 4 waves (2x2), 16x16x32 MFMA ----------------
// kind 0: A=hidB, BT=WT[z]; z=0->q [bh][s][160], z=1->k PADDED [bh][s][168], z=2->v^T [bh][d][s]
// kind 1: A=comb, BT=WoT;   out = A@Wo + bias -> fp32 d_out
__global__ __launch_bounds__(256, 2) void gemm128(
    const u16* __restrict__ A, const u16* __restrict__ BT,
    u16* __restrict__ dq, u16* __restrict__ dk, u16* __restrict__ dvt,
    float* __restrict__ dout, const float* __restrict__ bias, int kind)
{
  __shared__ __align__(16) u16 As[128*40];   // pad 32->40: 80B stride breaks conflicts
  __shared__ __align__(16) u16 Bs[128*40];
  int tid = threadIdx.x;
  int m0 = blockIdx.x*128, n0 = blockIdx.y*128;
  int z = blockIdx.z;
  const u16* Bt = BT + (size_t)z*1280*1280;
  int w = tid>>6, lane = tid&63, quad = lane>>4, l16 = lane&15;
  int wm = w&1, wn = w>>1;
  int arow = tid>>1, acg = (tid&1)*16;
  f32x4 zero = {0.f,0.f,0.f,0.f};
  f32x4 acc[4][4];
  #pragma unroll
  for (int a=0;a<4;a++) { acc[a][0]=zero; acc[a][1]=zero; acc[a][2]=zero; acc[a][3]=zero; }
  const u16* ga = A  + (size_t)(m0+arow)*1280 + acg;
  const u16* gb = Bt + (size_t)(n0+arow)*1280 + acg;
  for (int k0 = 0; k0 < 1280; k0 += 32) {
    uint4 a0 = *(const uint4*)(ga + k0);
    uint4 a1 = *(const uint4*)(ga + k0 + 8);
    uint4 b0 = *(const uint4*)(gb + k0);
    uint4 b1 = *(const uint4*)(gb + k0 + 8);
    __syncthreads();
    *(uint4*)&As[arow*40 + acg]     = a0;
    *(uint4*)&As[arow*40 + acg + 8] = a1;
    *(uint4*)&Bs[arow*40 + acg]     = b0;
    *(uint4*)&Bs[arow*40 + acg + 8] = b1;
    __syncthreads();
    bf16x8 af[4], bfr[4];
    #pragma unroll
    for (int mt=0; mt<4; mt++) af[mt]  = *(const bf16x8*)&As[(wm*64+mt*16+l16)*40 + quad*8];
    #pragma unroll
    for (int nt=0; nt<4; nt++) bfr[nt] = *(const bf16x8*)&Bs[(wn*64+nt*16+l16)*40 + quad*8];
    #pragma unroll
    for (int mt=0; mt<4; mt++)
      #pragma unroll
      for (int nt=0; nt<4; nt++)
        acc[mt][nt] = MFMA16(af[mt], bfr[nt], acc[mt][nt]);
  }
  #pragma unroll
  for (int mt=0; mt<4; mt++) {
    int r0g = m0 + wm*64 + mt*16 + quad*4;          // 4 consecutive rows (reg 0..3)
    #pragma unroll
    for (int nt=0; nt<4; nt++) {
      int col = n0 + wn*64 + nt*16 + l16;
      if (kind == 1) {
        float bi = bias[col];
        #pragma unroll
        for (int r=0;r<4;r++) dout[(size_t)(r0g+r)*1280 + col] = acc[mt][nt][r] + bi;
      } else {
        int h = col/160, d = col%160;
        if (z == 2) {                               // v -> [bh][d][s], s consecutive
          int b = r0g/2304, s0 = r0g%2304;
          size_t base = ((size_t)((b*8+h)*160 + d))*2304 + s0;
          ushort4 pk;
          pk.x = f2b(acc[mt][nt][0]); pk.y = f2b(acc[mt][nt][1]);
          pk.z = f2b(acc[mt][nt][2]); pk.w = f2b(acc[mt][nt][3]);
          *(ushort4*)&dvt[base] = pk;
        } else {
          #pragma unroll
          for (int r=0;r<4;r++) {
            int rg = r0g + r;
            int b = rg/2304, s = rg%2304;
            if (z == 0) dq[((size_t)(b*8+h)*2304 + s)*160  + d] = f2b(acc[mt][nt][r]);
            else        dk[((size_t)(b*8+h)*2304 + s)*KPAD + d] = f2b(acc[mt][nt][r]);
          }
        }
      }
    }
  }
}

// ---------------- Attention (flash-style, online softmax). ip=0: self -> hs (bf16).
// ip=1: keys=sksP, V=vst, per-key mask (bh%B tile quirk), combine -> comb bf16.
// K staged via global_load_lds DMA (padded rows, contiguous 21504B tiles);
// V B-frags direct from global (L1/L2 reuse). Zero VGPR-transit staging. --------
__global__ __launch_bounds__(256, 2) void attn(
    const u16* __restrict__ qg,   // [16][2304][160]
    const u16* __restrict__ kg,   // PADDED [16][2304][168]
    const u16* __restrict__ vtg,  // [16][160][2304]
    const float* __restrict__ maskkey, const float* __restrict__ mig,
    u16* __restrict__ hs, u16* __restrict__ comb,
    const void* scaleptr, int ip)
{
  __shared__ __align__(16) u16 Ks[64*KPAD];   // 21504 B, stride 84 dw -> 2-way free
  __shared__ __align__(16) u16 Ps[4*16*72];   // per-wave P relayout buffer
  int bh = blockIdx.y, qt = blockIdx.x;
  int tid = threadIdx.x, w = tid>>6, lane = tid&63, quad = lane>>4, l16 = lane&15;
  int q0 = qt*64 + w*16;                       // wave's 16 queries
  const float inv = 0.07905694150420949f;      // 1/sqrt(160)

  bf16x8 aq[5];                                // Q frags: A[m=l16][k=quad*8+j], 5 ksteps
  {
    const u16* qrow = qg + ((size_t)bh*2304 + q0 + l16)*160 + quad*8;
    #pragma unroll
    for (int ks=0; ks<5; ks++) aq[ks] = *(const bf16x8*)(qrow + ks*32);
  }
  f32x4 zero = {0.f,0.f,0.f,0.f};
  f32x4 o[10];
  #pragma unroll
  for (int i=0;i<10;i++) o[i] = zero;
  float mrun[4] = {-1e30f,-1e30f,-1e30f,-1e30f};
  float lrun[4] = {0.f,0.f,0.f,0.f};

  const u16* vbase = vtg + ((size_t)bh*160 + l16)*2304 + quad*8;   // + nt*16 rows + key offs
  const char* kgbytes = (const char*)kg;

  for (int kc = 0; kc < 36; kc++) {
    // ---- stage K[64 keys][168] tile via direct-to-LDS DMA (lane-linear copy) ----
    const char* tile = kgbytes + ((size_t)bh*2304 + (size_t)kc*64)*(KPAD*2);
    __syncthreads();                           // prior iter's Ks reads complete
    {
      int off = w*1024 + lane*16;
      #pragma unroll
      for (int j=0;j<5;j++)
        GLD16(tile + j*4096 + off, (char*)Ks + j*4096 + w*1024);
      if (w == 0)                               // 21504 - 20480 = 1024 B tail
        GLD16(tile + 20480 + lane*16, (char*)Ks + 20480);
    }
    __syncthreads();                           // drains own vmcnt, then barrier

    // ---- scores S[16 q][64 keys] = Q K^T * inv (+ mask) ----
    f32x4 sc[4];
    bool keep[4];
    #pragma unroll
    for (int nt=0; nt<4; nt++) {
      f32x4 s = zero;
      #pragma unroll
      for (int ks=0; ks<5; ks++) {
        bf16x8 bk = *(const bf16x8*)&Ks[(nt*16+l16)*KPAD + ks*32 + quad*8];
        s = MFMA16(aq[ks], bk, s);
      }
      #pragma unroll
      for (int r=0;r<4;r++) s[r] *= inv;
      keep[nt] = true;
      if (ip) {
        int key = kc*64 + nt*16 + l16;
        // diffusers .repeat(NH,1,1): mask batch index = bh % B, NOT bh/NH
        if (maskkey[(bh & 1)*2304 + key] == 0.0f) {
          keep[nt] = false;
          #pragma unroll
          for (int r=0;r<4;r++) s[r] = -1e30f;
        }
      }
      sc[nt] = s;
    }

    // ---- online softmax per query row (row = quad*4+r) ----
    float p[4][4];
    #pragma unroll
    for (int r=0;r<4;r++) {
      float mrow = fmaxf(fmaxf(sc[0][r], sc[1][r]), fmaxf(sc[2][r], sc[3][r]));
      #pragma unroll
      for (int off=1; off<16; off<<=1) mrow = fmaxf(mrow, __shfl_xor(mrow, off));
      float nm = fmaxf(mrun[r], mrow);
      float alpha = __expf(fminf(mrun[r] - nm, 0.f));
      mrun[r] = nm;
      float rs = 0.f;
      #pragma unroll
      for (int nt=0;nt<4;nt++) {
        float e = keep[nt] ? __expf(sc[nt][r] - nm) : 0.f;
        p[nt][r] = e; rs += e;
      }
      #pragma unroll
      for (int off=1; off<16; off<<=1) rs += __shfl_xor(rs, off);
      lrun[r] = lrun[r]*alpha + rs;
      #pragma unroll
      for (int nt2=0; nt2<10; nt2++) o[nt2][r] *= alpha;
    }

    // ---- P: C-layout -> A-layout via per-wave LDS (same-wave dep, compiler waits) ----
    #pragma unroll
    for (int nt=0;nt<4;nt++)
      #pragma unroll
      for (int r=0;r<4;r++)
        Ps[(w*16 + quad*4 + r)*72 + nt*16 + l16] = f2b(p[nt][r]);

    // ---- O += P V, V B-frags straight from global (16B/lane, L1/L2-resident tile) ----
    #pragma unroll
    for (int kb=0; kb<2; kb++) {
      bf16x8 ap = *(const bf16x8*)&Ps[(w*16 + l16)*72 + kb*32 + quad*8];
      #pragma unroll
      for (int nt=0; nt<10; nt++) {
        bf16x8 bv = *(const bf16x8*)(vbase + (size_t)nt*16*2304 + kc*64 + kb*32);
        o[nt] = MFMA16(ap, bv, o[nt]);
      }
    }
  }

  // ---- epilogue ----
  int b = bh>>3, h = bh&7;
  float scl = 0.f;
  if (ip) {                                   // scalar dtype self-detect (0.5 decodes both ways)
    u16 v0 = ((const u16*)scaleptr)[0];
    int e = (v0 >> 7) & 0xFF;
    scl = (v0 != 0 && e >= 100 && e <= 133) ? b2f(v0) : ((const float*)scaleptr)[0];
  }
  #pragma unroll
  for (int r=0;r<4;r++) {
    int s = q0 + quad*4 + r;
    float linv = (lrun[r] > 0.f) ? 1.0f/lrun[r] : 0.f;
    size_t base = ((size_t)b*2304 + s)*1280 + h*160;
    if (!ip) {
      #pragma unroll
      for (int nt=0;nt<10;nt++) hs[base + nt*16 + l16] = f2b(o[nt][r]*linv);
    } else {
      float f = mig[b*2304 + s]*scl*linv;    // mig uses TRUE b
      #pragma unroll
      for (int nt=0;nt<10;nt++)
        comb[base + nt*16 + l16] = f2b(b2f(hs[base + nt*16 + l16]) + o[nt][r]*f);
    }
  }
}

// ---------------- launch ----------------
extern "C" void kernel_launch(void* const* d_in, const int* in_sizes, int n_in,
                              void* d_out, int out_size, void* d_ws, size_t ws_size,
                              hipStream_t stream)
{
  const float* hid = (const float*)d_in[0];
  const float* Wq  = (const float*)d_in[1];
  const float* Wk  = (const float*)d_in[2];
  const float* Wv  = (const float*)d_in[3];
  const float* Wo  = (const float*)d_in[4];
  const float* bo  = (const float*)d_in[5];
  const float* sks = (const float*)d_in[6];
  const float* svs = (const float*)d_in[7];
  const void*  mid = d_in[8];
  const float* mig = (const float*)d_in[9];
  const void*  scl = d_in[10];

  char* ws = (char*)d_ws;                    // 69.9 MiB total (aliased, stream-ordered)
  float* mk   = (float*)(ws);                // [2][2304]              18432 B
  float* mg   = (float*)(ws + 18432);        // [2][2304]              18432 B
  u32*  mode  = (u32*)(ws + 36864);          // 256 B
  u16*  WT    = (u16*)(ws + 40960);          // 4 x 1280x1280 bf16  13107200 B
  u16*  slotA = (u16*)(ws + 13148160);       // hidB unpadded; later sksP padded  12386304
  u16*  q     = (u16*)(ws + 25534464);       // [16][2304][160]                   11796480
  u16*  slotB = (u16*)(ws + 37330944);       // kP padded; later comb             12386304
  u16*  vt    = (u16*)(ws + 49717248);       // v^T; later vst                    11796480
  u16*  hsB   = (u16*)(ws + 61513728);       // self-attn out bf16                11796480

  maskdet     <<<dim3(1),       256, 0, stream>>>((const u32*)mid, mode);
  maskprep    <<<dim3(18),      256, 0, stream>>>(mid, mig, mk, mg, mode);
  transpose_w <<<dim3(40,40,4), 256, 0, stream>>>(Wq, Wk, Wv, Wo, WT);
  conv        <<<dim3(2880),    256, 0, stream>>>(hid, slotA, 5898240);            // hidB
  gemm128     <<<dim3(36,10,3), 256, 0, stream>>>(slotA, WT, q, slotB, vt, nullptr, nullptr, 0);
  convK       <<<dim3(6048),    256, 0, stream>>>(sks, slotA);                     // hidB dead -> sksP
  attn        <<<dim3(36,16),   256, 0, stream>>>(q, slotB, vt, nullptr, nullptr, hsB, nullptr, scl, 0);
  transpose_vs<<<dim3(72,5,16), 256, 0, stream>>>(svs, vt);                        // vt dead -> vst
  attn        <<<dim3(36,16),   256, 0, stream>>>(q, slotA, vt, mk, mg, hsB, slotB, scl, 1); // kP dead -> comb
  gemm128     <<<dim3(36,10,1), 256, 0, stream>>>(slotB, WT + (size_t)3*1280*1280,
                                                  nullptr, nullptr, nullptr, (float*)d_out, bo, 1);
}